// Round 2
// baseline (130.737 us; speedup 1.0000x reference)
//
#include <hip/hip_runtime.h>

// YOLO loss: pred (B,30,7,7) f32, label (B,30,7,7) f32 -> scalar f32 (sum/B).
// Memory-bound: 96.3 MB read exactly once -> 15.3 us floor @6.3 TB/s.
// Timed graph also contains 2x256MiB harness poison fills (~82 us, fixed).
//
// R5 post-mortem: LDS staging (stage-all -> vmcnt(0) drain -> compute)
// REGRESSED (~+6 us): serialized memory phase, only 3 blocks/CU at 49 KB LDS.
// The R4 grid-stride flood (each wave issues all 60 scalar loads, ~245 KB/CU
// in flight) was already the right MLP regime. Reverted.
//
// R6 theory: R4 ran at 2.9 TB/s = exactly 2x the traffic model. Suspect
// dirty-L3 evictions: the two 256 MiB poison fills (L3-sized) precede us;
// cold reads evict dirty lines -> ~96 MB writebacks -> 192 MB effective.
// Fix: nontemporal loads (nt bit, no L2/L3 allocation) — data is read once,
// caching it is pure overhead regardless. Secondary: cls accumulated inline
// (no p[30]/l[30] arrays, label ch 9 unused) + __launch_bounds__(256,6)
// -> 24 waves/CU (was 16), 1568 blocks = exactly 1 cell/thread at B=8192.

constexpr int NT = 256;   // threads per block (4 waves)

__device__ __forceinline__ float sq(float x) { return x * x; }
__device__ __forceinline__ float ntl(const float* p) {
    return __builtin_nontemporal_load(p);
}

__global__ __launch_bounds__(NT, 6) void yolo_loss_kernel(
    const float* __restrict__ pred, const float* __restrict__ label,
    float* __restrict__ out, int ncells, float inv_B)
{
    const float Gc = 1.0f / 7.0f;
    float acc = 0.0f;

    const int g = blockIdx.x * NT + threadIdx.x;
    if (g < ncells) {
        int b = g / 49;
        int s = g - b * 49;
        int i = s / 7;          // axis 2, paired with x
        int j = s - i * 7;      // axis 3, paired with y
        const float* __restrict__ P = pred  + (size_t)b * 1470 + s;
        const float* __restrict__ L = label + (size_t)b * 1470 + s;

        // ch 0..9 of pred, ch 0..8 of label (label ch 9 is unused by the ref)
        float p[10], l[9];
#pragma unroll
        for (int c = 0; c < 10; ++c) p[c] = ntl(P + c * 49);
#pragma unroll
        for (int c = 0; c < 9; ++c)  l[c] = ntl(L + c * 49);

        // classes: accumulate inline, never hold ch 10..29 arrays
        float cls = 0.0f;
#pragma unroll
        for (int c = 10; c < 30; ++c) {
            float pc = ntl(P + c * 49);
            float lc = ntl(L + c * 49);
            cls += sq(pc - lc);
        }

        float fi = (float)i, fj = (float)j;

        // box 1 (pred ch 0..3)
        float cx1 = (p[0] + fi) * Gc, cy1 = (p[1] + fj) * Gc;
        float a_x1 = cx1 - p[2] * 0.5f, a_y1 = cy1 - p[3] * 0.5f;
        float a_x2 = cx1 + p[2] * 0.5f, a_y2 = cy1 + p[3] * 0.5f;
        // box 2 (pred ch 5..8)
        float cx2 = (p[5] + fi) * Gc, cy2 = (p[6] + fj) * Gc;
        float b_x1 = cx2 - p[7] * 0.5f, b_y1 = cy2 - p[8] * 0.5f;
        float b_x2 = cx2 + p[7] * 0.5f, b_y2 = cy2 + p[8] * 0.5f;
        // degenerate label point-box
        float lx = (l[0] + fi) * Gc - l[2] * 0.5f;
        float ly = (l[1] + fj) * Gc - l[3] * 0.5f;

        // iou(box, point-box) — faithful to reference (area_b = 0)
        auto iou_pt = [&](float x1, float y1, float x2, float y2) {
            float ix = fminf(x2, lx) - fmaxf(x1, lx);
            float iy = fminf(y2, ly) - fmaxf(y1, ly);
            float inter = fmaxf(ix, 0.0f) * fmaxf(iy, 0.0f);
            float area_a = (x2 - x1) * (y2 - y1);
            float uni = area_a + 0.0f - inter;
            float denom = (uni == 0.0f) ? 1.0f : uni;
            return inter / denom;
        };

        float iou1 = iou_pt(a_x1, a_y1, a_x2, a_y2);
        float iou2 = iou_pt(b_x1, b_y1, b_x2, b_y2);
        bool sel1 = iou1 > iou2;

        float t1 = sq(p[0] - l[0]) + sq(p[1] - l[1])
                 + sq(sqrtf(p[2]) - sqrtf(l[2])) + sq(sqrtf(p[3]) - sqrtf(l[3]));
        float t2 = sq(p[5] - l[5]) + sq(p[6] - l[6])
                 + sq(sqrtf(p[7]) - sqrtf(l[7])) + sq(sqrtf(p[8]) - sqrtf(l[8]));

        float obj_term     = sel1 ? t1 : t2;
        float conf_term    = sel1 ? sq(p[4] - 1.0f) : sq(p[9] - 1.0f);
        float noobj_obj    = sel1 ? sq(p[9]) : sq(p[4]);
        float noobj_empty  = sq(p[4]) + sq(p[9]);

        bool obj = (l[4] == 1.0f);
        // obj_weight = 0.5, noobj_weight = 0.5
        acc = obj ? (0.5f * obj_term + conf_term + cls + 0.5f * noobj_obj)
                  : (0.5f * noobj_empty);
    }

    // wave (64-lane) shuffle reduce
#pragma unroll
    for (int off = 32; off > 0; off >>= 1)
        acc += __shfl_down(acc, off, 64);

    __shared__ float swave[NT / 64];
    int lane = threadIdx.x & 63;
    int wid  = threadIdx.x >> 6;
    if (lane == 0) swave[wid] = acc;
    __syncthreads();
    if (threadIdx.x == 0) {
        float bs = 0.0f;
#pragma unroll
        for (int w = 0; w < NT / 64; ++w) bs += swave[w];
        atomicAdd(out, bs * inv_B);   // 1568 fire-and-forget atomics, staggered
    }
}

extern "C" void kernel_launch(void* const* d_in, const int* in_sizes, int n_in,
                              void* d_out, int out_size, void* d_ws, size_t ws_size,
                              hipStream_t stream) {
    const float* pred  = (const float*)d_in[0];
    const float* label = (const float*)d_in[1];
    float* out = (float*)d_out;

    int B = in_sizes[0] / 1470;
    int ncells = B * 49;
    int NB = (ncells + NT - 1) / NT;   // 1568 for B=8192, 1 cell/thread exactly

    hipMemsetAsync(d_out, 0, sizeof(float), stream);

    yolo_loss_kernel<<<NB, NT, 0, stream>>>(pred, label, out, ncells,
                                            1.0f / (float)B);
}

// Round 3
// 125.232 us; speedup vs baseline: 1.0440x; 1.0440x over previous
//
#include <hip/hip_runtime.h>

// YOLO loss: pred (B,30,7,7) f32, label (B,30,7,7) f32 -> scalar f32 (sum/B).
// Memory-bound: 96.3 MB read exactly once. Timed graph = 2x256MiB poison fills
// (~81.4 us fixed) + 4B memset + kernel. Kernel floor: 15.3 us @6.3 TB/s cold
// reads — but the fills leave L3 full of DIRTY poison (each fill's WRITE_SIZE
// = exactly 256 MiB = L3 size, i.e. it self-evicts while allocating), so our
// read-allocations force ~96 MB dirty writebacks -> ~30.5 us effective floor.
// R4 (this structure, plain loads) ran ~33 us: AT that forced-writeback roofline.
//
// R5 FAILED (+6): LDS stage->drain->compute serialized the memory phase.
// R6 FAILED (+15): nt loads + __launch_bounds__(256,6) cap bundled; the 85-VGPR
//   cap serialized the 60-load flood (MLP loss) and confounded the nt test.
//
// R7: verbatim R4 + nontemporal loads ONLY (single-variable ablation).
// If nt prevents L3 allocation: no dirty evictions -> kernel ~23 us.
// If nt only bypasses L2: +30-50% refetch (196B segments are 64B-misaligned,
// channel-boundary + wave-split lines fetched twice) -> kernel ~38 us.

constexpr int NT = 512;   // threads per block (8 waves)
constexpr int NB = 512;   // blocks (2 per CU, 16 waves/CU)

__device__ __forceinline__ float sq(float x) { return x * x; }
__device__ __forceinline__ float ntl(const float* p) {
    return __builtin_nontemporal_load(p);
}

__global__ __launch_bounds__(NT) void yolo_loss_kernel(
    const float* __restrict__ pred, const float* __restrict__ label,
    float* __restrict__ out, int ncells, float inv_B)
{
    const float Gc = 1.0f / 7.0f;
    float acc = 0.0f;

    for (int g = blockIdx.x * NT + threadIdx.x; g < ncells; g += NB * NT) {
        int b = g / 49;
        int s = g - b * 49;
        int i = s / 7;          // axis 2, paired with x
        int j = s - i * 7;      // axis 3, paired with y
        const float* __restrict__ P = pred  + (size_t)b * 1470 + s;
        const float* __restrict__ L = label + (size_t)b * 1470 + s;

        float p[30], l[30];
#pragma unroll
        for (int c = 0; c < 30; ++c) {
            p[c] = ntl(P + c * 49);
            l[c] = ntl(L + c * 49);
        }

        float fi = (float)i, fj = (float)j;

        // box 1 (pred ch 0..3)
        float cx1 = (p[0] + fi) * Gc, cy1 = (p[1] + fj) * Gc;
        float a_x1 = cx1 - p[2] * 0.5f, a_y1 = cy1 - p[3] * 0.5f;
        float a_x2 = cx1 + p[2] * 0.5f, a_y2 = cy1 + p[3] * 0.5f;
        // box 2 (pred ch 5..8)
        float cx2 = (p[5] + fi) * Gc, cy2 = (p[6] + fj) * Gc;
        float b_x1 = cx2 - p[7] * 0.5f, b_y1 = cy2 - p[8] * 0.5f;
        float b_x2 = cx2 + p[7] * 0.5f, b_y2 = cy2 + p[8] * 0.5f;
        // degenerate label point-box
        float lx = (l[0] + fi) * Gc - l[2] * 0.5f;
        float ly = (l[1] + fj) * Gc - l[3] * 0.5f;

        // iou(box, point-box) — faithful to reference (area_b = 0)
        auto iou_pt = [&](float x1, float y1, float x2, float y2) {
            float ix = fminf(x2, lx) - fmaxf(x1, lx);
            float iy = fminf(y2, ly) - fmaxf(y1, ly);
            float inter = fmaxf(ix, 0.0f) * fmaxf(iy, 0.0f);
            float area_a = (x2 - x1) * (y2 - y1);
            float uni = area_a + 0.0f - inter;
            float denom = (uni == 0.0f) ? 1.0f : uni;
            return inter / denom;
        };

        float iou1 = iou_pt(a_x1, a_y1, a_x2, a_y2);
        float iou2 = iou_pt(b_x1, b_y1, b_x2, b_y2);
        bool sel1 = iou1 > iou2;

        float t1 = sq(p[0] - l[0]) + sq(p[1] - l[1])
                 + sq(sqrtf(p[2]) - sqrtf(l[2])) + sq(sqrtf(p[3]) - sqrtf(l[3]));
        float t2 = sq(p[5] - l[5]) + sq(p[6] - l[6])
                 + sq(sqrtf(p[7]) - sqrtf(l[7])) + sq(sqrtf(p[8]) - sqrtf(l[8]));

        float obj_term     = sel1 ? t1 : t2;
        float conf_term    = sel1 ? sq(p[4] - 1.0f) : sq(p[9] - 1.0f);
        float noobj_obj    = sel1 ? sq(p[9]) : sq(p[4]);
        float noobj_empty  = sq(p[4]) + sq(p[9]);

        float cls = 0.0f;
#pragma unroll
        for (int c = 10; c < 30; ++c) cls += sq(p[c] - l[c]);

        bool obj = (l[4] == 1.0f);
        // obj_weight = 0.5, noobj_weight = 0.5
        acc += obj ? (0.5f * obj_term + conf_term + cls + 0.5f * noobj_obj)
                   : (0.5f * noobj_empty);
    }

    // wave (64-lane) shuffle reduce
#pragma unroll
    for (int off = 32; off > 0; off >>= 1)
        acc += __shfl_down(acc, off, 64);

    __shared__ float swave[NT / 64];
    int lane = threadIdx.x & 63;
    int wid  = threadIdx.x >> 6;
    if (lane == 0) swave[wid] = acc;
    __syncthreads();
    if (threadIdx.x == 0) {
        float bs = 0.0f;
#pragma unroll
        for (int w = 0; w < NT / 64; ++w) bs += swave[w];
        atomicAdd(out, bs * inv_B);   // 512 atomics total, staggered
    }
}

extern "C" void kernel_launch(void* const* d_in, const int* in_sizes, int n_in,
                              void* d_out, int out_size, void* d_ws, size_t ws_size,
                              hipStream_t stream) {
    const float* pred  = (const float*)d_in[0];
    const float* label = (const float*)d_in[1];
    float* out = (float*)d_out;

    int B = in_sizes[0] / 1470;
    int ncells = B * 49;

    hipMemsetAsync(d_out, 0, sizeof(float), stream);

    yolo_loss_kernel<<<NB, NT, 0, stream>>>(pred, label, out, ncells,
                                            1.0f / (float)B);
}

// Round 4
// 114.658 us; speedup vs baseline: 1.1402x; 1.0922x over previous
//
#include <hip/hip_runtime.h>

// YOLO loss: pred (B,30,7,7) f32, label (B,30,7,7) f32 -> scalar f32 (sum/B).
// Memory-bound: 96.3 MB read exactly once. Timed graph = 2x256MiB harness
// poison fills (~81.4 us, fixed) + 4B memset + kernel.
//
// Kernel floor is NOT 15.3 us: the fills leave L3 (256 MiB) entirely DIRTY
// (each fill's own WRITE_SIZE = exactly 256 MiB at 6.5 TB/s = self-evicting
// while allocating). Our 96 MB of read-allocations force ~96 MB dirty
// writebacks concurrent with the reads -> ~192 MB effective -> ~30.5 us floor.
// This kernel runs ~33 us: within ~8% of that harness-conditioned roofline.
//
// Ablation ledger (kernel-inferred times, fills subtracted):
//   R4 flood + plain loads        ~33 us  <- BEST (this file)
//   R5 LDS stage->drain->compute  ~39 us  (serialized memory phase)
//   R6 nt + __launch_bounds__ cap ~46 us  (VGPR cap kills 60-load MLP)
//   R7 nt loads only              ~43 us  (nt = L2 bypass -> split-line refetch;
//                                          no L3-allocation-policy benefit)
// Structure: 512x512 grid-stride flood. Each thread issues all 60 stride-49
// dword loads up front (~245 KB/CU in flight, >> BW*latency product); 64
// consecutive cells/wave -> contiguous 196-256 B segments, fully coalesced.
// L2 absorbs channel-boundary/wave-split line sharing. Plain loads, default
// launch bounds (VGPR headroom for the flood), 512 staggered atomics.

constexpr int NT = 512;   // threads per block (8 waves)
constexpr int NB = 512;   // blocks (2 per CU, 16 waves/CU)

__device__ __forceinline__ float sq(float x) { return x * x; }

__global__ __launch_bounds__(NT) void yolo_loss_kernel(
    const float* __restrict__ pred, const float* __restrict__ label,
    float* __restrict__ out, int ncells, float inv_B)
{
    const float Gc = 1.0f / 7.0f;
    float acc = 0.0f;

    for (int g = blockIdx.x * NT + threadIdx.x; g < ncells; g += NB * NT) {
        int b = g / 49;
        int s = g - b * 49;
        int i = s / 7;          // axis 2, paired with x
        int j = s - i * 7;      // axis 3, paired with y
        const float* __restrict__ P = pred  + (size_t)b * 1470 + s;
        const float* __restrict__ L = label + (size_t)b * 1470 + s;

        float p[30], l[30];
#pragma unroll
        for (int c = 0; c < 30; ++c) {
            p[c] = P[c * 49];
            l[c] = L[c * 49];
        }

        float fi = (float)i, fj = (float)j;

        // box 1 (pred ch 0..3)
        float cx1 = (p[0] + fi) * Gc, cy1 = (p[1] + fj) * Gc;
        float a_x1 = cx1 - p[2] * 0.5f, a_y1 = cy1 - p[3] * 0.5f;
        float a_x2 = cx1 + p[2] * 0.5f, a_y2 = cy1 + p[3] * 0.5f;
        // box 2 (pred ch 5..8)
        float cx2 = (p[5] + fi) * Gc, cy2 = (p[6] + fj) * Gc;
        float b_x1 = cx2 - p[7] * 0.5f, b_y1 = cy2 - p[8] * 0.5f;
        float b_x2 = cx2 + p[7] * 0.5f, b_y2 = cy2 + p[8] * 0.5f;
        // degenerate label point-box
        float lx = (l[0] + fi) * Gc - l[2] * 0.5f;
        float ly = (l[1] + fj) * Gc - l[3] * 0.5f;

        // iou(box, point-box) — faithful to reference (area_b = 0)
        auto iou_pt = [&](float x1, float y1, float x2, float y2) {
            float ix = fminf(x2, lx) - fmaxf(x1, lx);
            float iy = fminf(y2, ly) - fmaxf(y1, ly);
            float inter = fmaxf(ix, 0.0f) * fmaxf(iy, 0.0f);
            float area_a = (x2 - x1) * (y2 - y1);
            float uni = area_a + 0.0f - inter;
            float denom = (uni == 0.0f) ? 1.0f : uni;
            return inter / denom;
        };

        float iou1 = iou_pt(a_x1, a_y1, a_x2, a_y2);
        float iou2 = iou_pt(b_x1, b_y1, b_x2, b_y2);
        bool sel1 = iou1 > iou2;

        float t1 = sq(p[0] - l[0]) + sq(p[1] - l[1])
                 + sq(sqrtf(p[2]) - sqrtf(l[2])) + sq(sqrtf(p[3]) - sqrtf(l[3]));
        float t2 = sq(p[5] - l[5]) + sq(p[6] - l[6])
                 + sq(sqrtf(p[7]) - sqrtf(l[7])) + sq(sqrtf(p[8]) - sqrtf(l[8]));

        float obj_term     = sel1 ? t1 : t2;
        float conf_term    = sel1 ? sq(p[4] - 1.0f) : sq(p[9] - 1.0f);
        float noobj_obj    = sel1 ? sq(p[9]) : sq(p[4]);
        float noobj_empty  = sq(p[4]) + sq(p[9]);

        float cls = 0.0f;
#pragma unroll
        for (int c = 10; c < 30; ++c) cls += sq(p[c] - l[c]);

        bool obj = (l[4] == 1.0f);
        // obj_weight = 0.5, noobj_weight = 0.5
        acc += obj ? (0.5f * obj_term + conf_term + cls + 0.5f * noobj_obj)
                   : (0.5f * noobj_empty);
    }

    // wave (64-lane) shuffle reduce
#pragma unroll
    for (int off = 32; off > 0; off >>= 1)
        acc += __shfl_down(acc, off, 64);

    __shared__ float swave[NT / 64];
    int lane = threadIdx.x & 63;
    int wid  = threadIdx.x >> 6;
    if (lane == 0) swave[wid] = acc;
    __syncthreads();
    if (threadIdx.x == 0) {
        float bs = 0.0f;
#pragma unroll
        for (int w = 0; w < NT / 64; ++w) bs += swave[w];
        atomicAdd(out, bs * inv_B);   // 512 atomics total, staggered
    }
}

extern "C" void kernel_launch(void* const* d_in, const int* in_sizes, int n_in,
                              void* d_out, int out_size, void* d_ws, size_t ws_size,
                              hipStream_t stream) {
    const float* pred  = (const float*)d_in[0];
    const float* label = (const float*)d_in[1];
    float* out = (float*)d_out;

    int B = in_sizes[0] / 1470;
    int ncells = B * 49;

    hipMemsetAsync(d_out, 0, sizeof(float), stream);

    yolo_loss_kernel<<<NB, NT, 0, stream>>>(pred, label, out, ncells,
                                            1.0f / (float)B);
}